// Round 12
// baseline (208.275 us; speedup 1.0000x reference)
//
#include <hip/hip_runtime.h>
#include <math.h>

#define NSAMP 32768
#define NPAD  65536
#define NCH   128
#define TWO_PI 6.2831853071795864f
#define MINF ((float)(20.0/11025.0))
#define DRF  ((float)(4000.0/11025.0 - 20.0/11025.0))

__device__ __forceinline__ float2 cxmul(float2 a, float2 b){
    return make_float2(a.x*b.x - a.y*b.y, a.x*b.y + a.y*b.x);
}

template<int DIR>
__device__ __forceinline__ void fft4v(float2* v, int i0, int i1, int i2, int i3){
    float2 a=v[i0], b=v[i1], c=v[i2], d=v[i3];
    float2 t0 = make_float2(a.x+c.x, a.y+c.y);
    float2 t1 = make_float2(a.x-c.x, a.y-c.y);
    float2 t2 = make_float2(b.x+d.x, b.y+d.y);
    float2 t3 = make_float2(b.x-d.x, b.y-d.y);
    v[i0] = make_float2(t0.x+t2.x, t0.y+t2.y);
    v[i2] = make_float2(t0.x-t2.x, t0.y-t2.y);
    if (DIR < 0) {
        v[i1] = make_float2(t1.x + t3.y, t1.y - t3.x);
        v[i3] = make_float2(t1.x - t3.y, t1.y + t3.x);
    } else {
        v[i1] = make_float2(t1.x - t3.y, t1.y + t3.x);
        v[i3] = make_float2(t1.x + t3.y, t1.y - t3.x);
    }
}

template<int DIR>
__device__ __forceinline__ void twm(float2& v, float c, float s){
    float sy = (DIR<0) ? -s : s;
    v = cxmul(v, make_float2(c, sy));
}

template<int DIR>
__device__ __forceinline__ void fft16r(float2* v){
    const float C1=0.92387953251128674f, S1=0.38268343236508978f, H=0.70710678118654752f;
    fft4v<DIR>(v,0,4,8,12);
    fft4v<DIR>(v,1,5,9,13);
    fft4v<DIR>(v,2,6,10,14);
    fft4v<DIR>(v,3,7,11,15);
    twm<DIR>(v[5],  C1, S1);
    twm<DIR>(v[6],  H,  H);
    twm<DIR>(v[7],  S1, C1);
    twm<DIR>(v[9],  H,  H);
    twm<DIR>(v[10], 0.0f, 1.0f);
    twm<DIR>(v[11], -H, H);
    twm<DIR>(v[13], S1, C1);
    twm<DIR>(v[14], -H, H);
    twm<DIR>(v[15], -C1, -S1);
    fft4v<DIR>(v,0,1,2,3);
    fft4v<DIR>(v,4,5,6,7);
    fft4v<DIR>(v,8,9,10,11);
    fft4v<DIR>(v,12,13,14,15);
    // X[r] at slot ((r&3)<<2)|(r>>2)
}

template<int DIR>
__device__ __forceinline__ void fft8r(float2* v){
    const float H=0.70710678118654752f;
    #pragma unroll
    for (int n1=0;n1<4;n1++){
        float2 t=v[n1], u=v[n1+4];
        v[n1]   = make_float2(t.x+u.x, t.y+u.y);
        v[n1+4] = make_float2(t.x-u.x, t.y-u.y);
    }
    twm<DIR>(v[5], H, H);
    twm<DIR>(v[6], 0.0f, 1.0f);
    twm<DIR>(v[7], -H, H);
    fft4v<DIR>(v,0,1,2,3);
    fft4v<DIR>(v,4,5,6,7);
    // X[r] at slot ((r&1)<<2)|(r>>1)
}

__device__ __forceinline__ int slot16(int r){ return ((r&3)<<2)|(r>>2); }
__device__ __forceinline__ int slot8(int r){ return ((r&1)<<2)|(r>>1); }
// XOR swizzle: same bank spread as +pad, LDS stays exactly 4096 float2 (32 KB).
__device__ __forceinline__ int lxs(int l){ return l ^ ((l>>4)&15); }

// twiddle powers: 1 sincos + log-depth complex-power recurrence
template<int R>
__device__ __forceinline__ void twiddle(float2* v, float ang1){
    float s,c; __sincosf(ang1,&s,&c);
    float2 w[R];
    w[1] = make_float2(c,s);
    #pragma unroll
    for (int r=2;r<R;r++) w[r] = cxmul(w[r>>1], w[r-(r>>1)]);
    #pragma unroll
    for (int r=1;r<R;r++) v[r] = cxmul(v[r], w[r]);
}

// Double-stage tail for (Ns=1, Ns=16): stage A (no twiddle) -> LDS -> stage B -> store.
template<int DIR>
__device__ __forceinline__ void n1_tail(float2 (&v)[16], float2* lds, int t, int p,
                                        float2* __restrict__ out)
{
    fft16r<DIR>(v);
    #pragma unroll
    for (int r=0;r<16;r++) lds[lxs(256*(t>>4) + 16*(t&15) + r)] = v[slot16(r)];
    __syncthreads();
    #pragma unroll
    for (int q=0;q<16;q++) v[q] = lds[lxs(256*q + t)];
    int jm = t & 15;
    if (jm) twiddle<16>(v, (DIR<0?-TWO_PI:TWO_PI)*(float)jm*(1.0f/256.0f));
    fft16r<DIR>(v);
    int j2 = 256*p + t;
    float2* yo = out + (j2>>4)*256 + (j2&15);
    #pragma unroll
    for (int r=0;r<16;r++) yo[16*r] = v[slot16(r)];
}

// ---------------- N1 noise + full parameter setup (blocks 8..15) ----------------
// cum stored TRANSPOSED: cum[jj*2048 + q]  (coalesced writes and loads)
__global__ __launch_bounds__(256) void mfk_n1_noise_setup(const float* __restrict__ noise,
        float2* __restrict__ dst, const float* __restrict__ EP,
        const float* __restrict__ MXR, const float* __restrict__ RL,
        float* __restrict__ chP, unsigned* __restrict__ chQ, float* __restrict__ chR,
        float* __restrict__ cum, float* __restrict__ mxA, float* __restrict__ rmA)
{
    __shared__ float2 lds[4096];
    int t = threadIdx.x, px = blockIdx.x;
    if (px >= 8){
        int q = (px-8)*256 + t;          // chain id 0..2047
        int c = q >> 4, h = q & 15;
        const float* P = EP + c*22;
        const float LSQ = (float)0.9189385332046727;
        float f0m = __fmul_rn(P[4],P[4]);
        float f0s = __fadd_rn(MINF, __fmul_rn(f0m, DRF));
        float fr  = __fmul_rn(f0s, (float)(h+1));
        if (fr >= 1.0f) fr = 0.0f;
        chQ[q] = (unsigned)(unsigned long long)((double)fr*4294967296.0 + 0.5);
        float rs = __fadd_rn(__fmul_rn(P[6+h],0.2f),0.8f);
        chR[q] = rs;
        float cp = rs;
        for (int jj=0;jj<128;jj++){ cum[(size_t)jj*2048 + q] = cp; cp = __fmul_rn(cp, rs); }
        if (h == 0){
            float fm  = __fmul_rn(P[0],P[0]);
            float fmu = __fadd_rn(MINF, __fmul_rn(fm, DRF));
            float fsg = 1e-8f + P[1]*0.1f;
            float fsi = 1.0f/fsg;
            int i0 = (int)floorf(fmu*16384.0f + 0.5f);
            i0 = min(max(i0,0),16384);
            float rg = (float)i0 * (1.0f/16384.0f);
            float tt = (rg - fmu)*fsi;
            float Lc = logf(fsg) + LSQ;
            float sc = expf(-Lc) / (expf(-0.5f*tt*tt - Lc) + 1e-8f);
            float tmu = P[2];
            float tsg = 1e-8f + P[3]*0.1f;
            float tsi = 1.0f/tsg;
            int i1 = (int)floorf(tmu*32767.0f + 0.5f);
            i1 = min(max(i1,0),32767);
            float rg1 = (float)((double)i1 * (1.0/32767.0));
            float tt1 = (rg1 - tmu)*tsi;
            float Lc1 = logf(tsg) + LSQ;
            float sc1 = expf(-Lc1) / (expf(-0.5f*tt1*tt1 - Lc1) + 1e-8f);
            float amp = P[5]*P[5];
            float* o = chP + c*8;
            o[0]=fmu; o[1]=fsi; o[2]=sc; o[3]=tmu; o[4]=tsi; o[5]=sc1; o[6]=amp; o[7]=0.f;
        }
        if (q < 4){
            int b = q;
            mxA[b] = 1.0f/(1.0f + expf(-MXR[b]));
            const float* rl = RL + b*8;
            float mx = rl[0];
            for (int r=1;r<8;r++) mx = fmaxf(mx, rl[r]);
            float sum=0.f;
            float e2[8];
            for (int r=0;r<8;r++){ e2[r]=expf(rl[r]-mx); sum+=e2[r]; }
            for (int r=0;r<8;r++) rmA[b*8+r] = e2[r]/sum;
        }
        return;
    }
    int p = px;
    int j = 128*(t>>4) + 16*p + (t&15);
    float2 v[16];
    #pragma unroll
    for (int r=0;r<16;r++) v[r] = make_float2(noise[j + 2048*r], 0.0f);
    n1_tail<-1>(v, lds, t, p, dst);
}

__global__ __launch_bounds__(256) void mfk_n1_specwin(const float2* __restrict__ nspec,
        const float* __restrict__ chP, float2* __restrict__ dst, int g0)
{
    __shared__ float2 lds[4096];
    int t = threadIdx.x, p = blockIdx.x, pr = blockIdx.y;
    int c0 = g0 + 2*pr;
    const float* A = chP + c0*8;
    const float* B = chP + (c0+1)*8;
    float a0=A[0], a1=A[1], a2=A[2], b0=B[0], b1=B[1], b2=B[2];
    int j = 128*(t>>4) + 16*p + (t&15);
    float2 v[16];
    #pragma unroll
    for (int r=0;r<16;r++){
        int k = j + 2048*r;
        int kw = (k <= 16384) ? k : (32768 - k);
        float rg = (float)kw * (1.0f/16384.0f);
        float t0 = (rg - a0)*a1;
        float w0 = expf(-0.5f*t0*t0)*a2;
        float t1 = (rg - b0)*b1;
        float w1 = expf(-0.5f*t1*t1)*b2;
        float2 N = nspec[k];
        v[r] = make_float2(N.x*w0 - N.y*w1, N.y*w0 + N.x*w1);
    }
    n1_tail<1>(v, lds, t, p, dst + (size_t)pr*NSAMP);
}

// N2: stages (Ns=256 R16, Ns=4096 R8). Stage C: j2 = 256*(t>>5)+32p+(t&31).
template<int DIR>
__device__ __forceinline__ void n2_stageC(const float2* __restrict__ x, float2* lds, int t, int p)
{
    float2 v[16];
    int j2 = 256*(t>>5) + 32*p + (t&31);
    #pragma unroll
    for (int r=0;r<16;r++) v[r] = x[j2 + 2048*r];
    int jm = 32*p + (t&31);
    if (jm) twiddle<16>(v, (DIR<0?-TWO_PI:TWO_PI)*(float)jm*(1.0f/4096.0f));
    fft16r<DIR>(v);
    #pragma unroll
    for (int r=0;r<16;r++) lds[lxs(256*r + t)] = v[slot16(r)];
    __syncthreads();
}

template<int DIR>
__device__ __forceinline__ int n2_stageD(float2* lds, int t, int p, int u, float2 (&w8)[8])
{
    int q = t + 256*u;
    int j3 = ((q>>5)<<8) + 32*p + (q&31);
    #pragma unroll
    for (int r3=0;r3<8;r3++) w8[r3] = lds[lxs(256*(q>>5) + 32*r3 + (q&31))];
    if (j3) twiddle<8>(w8, (DIR<0?-TWO_PI:TWO_PI)*(float)j3*(1.0f/32768.0f));
    fft8r<DIR>(w8);
    return j3;
}

__global__ __launch_bounds__(256) void mfk_n2_noise(const float2* __restrict__ src,
                                                    float2* __restrict__ dst)
{
    __shared__ float2 lds[4096];
    int t = threadIdx.x, p = blockIdx.x;
    n2_stageC<-1>(src, lds, t, p);
    #pragma unroll
    for (int u=0;u<2;u++){
        float2 w8[8];
        int j3 = n2_stageD<-1>(lds, t, p, u, w8);
        #pragma unroll
        for (int r=0;r<8;r++) dst[j3 + 4096*r] = w8[slot8(r)];
    }
}

__global__ __launch_bounds__(256) void mfk_n2_unpack(const float2* __restrict__ src,
        const float* __restrict__ chP, float* __restrict__ locraw, int g0)
{
    __shared__ float2 lds[4096];
    int t = threadIdx.x, p = blockIdx.x, pr = blockIdx.y;
    n2_stageC<1>(src + (size_t)pr*NSAMP, lds, t, p);
    int lc0 = 2*pr;
    const float* C0 = chP + (g0+lc0)*8;
    const float* C1 = chP + (g0+lc0+1)*8;
    float c03=C0[3], c04=C0[4], c05=C0[5], c06=C0[6];
    float c13=C1[3], c14=C1[4], c15=C1[5], c16=C1[6];
    #pragma unroll
    for (int u=0;u<2;u++){
        float2 w8[8];
        int j3 = n2_stageD<1>(lds, t, p, u, w8);
        #pragma unroll
        for (int r=0;r<8;r++){
            int n = j3 + 4096*r;
            float2 val = w8[slot8(r)];
            float rg = (float)((double)n * (1.0/32767.0));
            float tt0 = (rg - c03)*c04;
            float ew0 = expf(-0.5f*tt0*tt0)*c05;
            float tt1 = (rg - c13)*c14;
            float ew1 = expf(-0.5f*tt1*tt1)*c15;
            locraw[(size_t)lc0*NSAMP + n]     = val.x*(1.0f/32768.0f)*ew0*c06;
            locraw[(size_t)(lc0+1)*NSAMP + n] = val.y*(1.0f/32768.0f)*ew1*c16;
        }
    }
}

// ---------------- NPAD kernels ----------------
// packZ + in-register resonance synthesis + stages (Ns=1,16) of 65536-FFT.
// cum table: transposed global [jj][q], LDS [jj][hh]; qS/rS union'd into lds (32 KB total).
__global__ __launch_bounds__(256) void mfk_packZres_f01(const float* __restrict__ locraw,
        const unsigned* __restrict__ chQ, const float* __restrict__ chR,
        const float* __restrict__ cum, float2* __restrict__ dst, int g0)
{
    __shared__ float2 lds[4096];
    float* cumS = (float*)lds;                      // floats [0,2048): [jj][hh]
    unsigned* qS = (unsigned*)(cumS + 2048);        // floats [2048,2064)
    float* rS = cumS + 2064;                        // floats [2064,2080)
    int t = threadIdx.x, p = blockIdx.x, lc = blockIdx.y;
    int cg = g0 + lc;
    #pragma unroll
    for (int i=0;i<8;i++){
        int jj = (t>>4) + 16*i;
        cumS[jj*16 + (t&15)] = cum[(size_t)jj*2048 + cg*16 + (t&15)];
    }
    if (t < 16){ qS[t] = chQ[cg*16 + t]; rS[t] = chR[cg*16 + t]; }
    __syncthreads();
    int j = 256*(t>>4) + 16*p + (t&15);
    // co advances by exactly +16 per r-step; wf r-invariant. ilo in {-1, 0..15}.
    float co0 = ((float)j + 0.5f)*0.00390625f - 0.5f;
    float fl = floorf(co0);
    float wf = co0 - fl;
    int ilo = (int)fl;
    float acc[8];
    #pragma unroll
    for (int r=0;r<8;r++) acc[r] = 0.0f;
    if (j == 0) acc[0] = 1.0f;   // +delta carries the residual "+located" through conv
    unsigned T1 = (unsigned)(j+1);
    #pragma unroll
    for (int hh=0; hh<16; hh++){
        unsigned qq = qS[hh];
        float rs = rS[hh];
        float rs2 = rs*rs, rs4 = rs2*rs2, rs8 = rs4*rs4, rs16 = rs8*rs8;
        float mix = fmaf(rs - 1.0f, wf, 1.0f);
        unsigned bits = qq * T1;
        unsigned step = qq << 12;
        float e_cur = (ilo >= 0) ? cumS[ilo*16 + hh] : cumS[15*16 + hh];
        float env0  = (ilo >= 0) ? 0.0f : cumS[hh];   // only used when ilo<0, r=0
        #pragma unroll
        for (int r=0;r<8;r++){
            float env;
            if (r == 0 && ilo < 0) env = env0;                       // low clamp: wf=0
            else env = (ilo == 15 && r == 7) ? e_cur : e_cur*mix;    // high clamp at lo=127
            float m = (float)bits * 2.3283064365386963e-10f;
            float sv; asm("v_sin_f32 %0, %1" : "=v"(sv) : "v"(m));
            acc[r] = fmaf(env, sv, acc[r]);
            bits += step;
            if (!(r == 0 && ilo < 0)) e_cur *= rs16;
        }
    }
    const float* la = locraw + (size_t)lc*NSAMP;
    float2 v[16];
    #pragma unroll
    for (int r=0;r<8;r++) v[r] = make_float2(la[j + 4096*r], acc[r]);
    #pragma unroll
    for (int r=8;r<16;r++) v[r] = make_float2(0.f,0.f);
    __syncthreads();                       // cumS/qS/rS reads done before lds reuse
    n1_tail<-1>(v, lds, t, p, dst + (size_t)lc*NPAD);
}

// stages (Ns=256, 4096) of 65536-FFT; NSTORE=8 skips discarded upper half.
template<int DIR, int NSTORE>
__global__ __launch_bounds__(256) void mfk_f23(const float2* __restrict__ src,
                                               float2* __restrict__ dst)
{
    __shared__ float2 lds[4096];
    int t = threadIdx.x, p = blockIdx.x;
    size_t boff = (size_t)blockIdx.y * NPAD;
    int a = t>>4, w = t&15;
    int j = 256*a + 16*p + w;
    const float2* x = src + boff;
    float2 v[16];
    #pragma unroll
    for (int r=0;r<16;r++) v[r] = x[j + 4096*r];
    int jm = 16*p + w;
    if (jm) twiddle<16>(v, (DIR<0?-TWO_PI:TWO_PI)*(float)jm*(1.0f/4096.0f));
    fft16r<DIR>(v);
    #pragma unroll
    for (int r=0;r<16;r++) lds[lxs(256*a + 16*r + w)] = v[slot16(r)];
    __syncthreads();
    #pragma unroll
    for (int q=0;q<16;q++) v[q] = lds[lxs(256*q + t)];
    if (j) twiddle<16>(v, (DIR<0?-TWO_PI:TWO_PI)*(float)j*(1.0f/65536.0f));
    fft16r<DIR>(v);
    float2* yo = dst + boff + j;
    #pragma unroll
    for (int r=0;r<NSTORE;r++) yo[4096*r] = v[slot16(r)];
}

// ---------------- spectral product + event-sum (linearity) ----------------
// S_b[k] = sum_e A_e[k]*R_e[k]; batches packed: T = S_{2beta} + i*S_{2beta+1}.
// grid (256, 2 beta, 2 z-half); mirror-paired blocks share an XCD (x ^ 8).
__global__ __launch_bounds__(256) void mfk_prodacc(const float2* __restrict__ Z,
        float2* __restrict__ T, int g0, int G, int addTo)
{
    int x = blockIdx.x;
    int beta = blockIdx.y;
    int z = blockIdx.z;
    int g = ((x>>4)<<3) | (x&7);
    int kb = (x&8) ? (255 - g) : g;
    int k = kb*256 + threadIdx.x;
    int km = (NPAD - k) & (NPAD-1);
    int cstart = max(64*beta + 32*z, g0);
    int cend   = min(64*beta + 32*z + 32, g0+G);
    float2 S0 = make_float2(0.f,0.f), S1 = make_float2(0.f,0.f);
    #pragma unroll 4
    for (int c=cstart; c<cend; ++c){
        const float2* zp = Z + (size_t)(c-g0)*NPAD;
        float2 a = zp[k], am = zp[km];
        float2 A0 = make_float2(0.5f*(a.x+am.x), 0.5f*(a.y-am.y));
        float2 R0 = make_float2(0.5f*(a.y+am.y), -0.5f*(a.x-am.x));
        float2 P = cxmul(A0,R0);
        if ((c>>5)&1){ S1.x += P.x; S1.y += P.y; }
        else         { S0.x += P.x; S0.y += P.y; }
    }
    const float s = 1.0f/65536.0f;
    float2 q = make_float2((S0.x - S1.y)*s, (S0.y + S1.x)*s);
    size_t idx = ((size_t)z*2 + beta)*NPAD + k;
    if (addTo){ float2 o = T[idx]; q.x += o.x; q.y += o.y; }
    T[idx] = q;
}

// plain first inverse pair (Ns=1,16), summing the two z-half partial spectra
__global__ __launch_bounds__(256) void mfk_plain_f01(const float2* __restrict__ T,
        float2* __restrict__ dst)
{
    __shared__ float2 lds[4096];
    int t = threadIdx.x, p = blockIdx.x, b = blockIdx.y;
    const float2* x0 = T + (size_t)b*NPAD;
    const float2* x1 = T + (size_t)(2+b)*NPAD;
    int j = 256*(t>>4) + 16*p + (t&15);
    float2 v[16];
    #pragma unroll
    for (int r=0;r<16;r++){
        float2 u0 = x0[j + 4096*r], u1 = x1[j + 4096*r];
        v[r] = make_float2(u0.x+u1.x, u0.y+u1.y);
    }
    n1_tail<1>(v, lds, t, p, dst + (size_t)b*NPAD);
}

// FUSED: f23<1,8> (finishing located inverse FFT) -> store U2 -> drypack both
// batches of the pair -> two n1_tail stage-A passes of the wet forward FFT.
__global__ __launch_bounds__(256) void mfk_f23U2_dry(const float2* __restrict__ src,
        const float* __restrict__ rmA, const float* __restrict__ IR,
        float2* __restrict__ U2, float2* __restrict__ dstA)
{
    __shared__ float2 lds[4096];
    int t = threadIdx.x, p = blockIdx.x, pr = blockIdx.y;
    size_t boff = (size_t)pr * NPAD;
    int a = t>>4, w = t&15;
    int j = 256*a + 16*p + w;
    const float2* x = src + boff;
    float2 v[16];
    #pragma unroll
    for (int r=0;r<16;r++) v[r] = x[j + 4096*r];
    int jm = 16*p + w;
    if (jm) twiddle<16>(v, TWO_PI*(float)jm*(1.0f/4096.0f));
    fft16r<1>(v);
    #pragma unroll
    for (int r=0;r<16;r++) lds[lxs(256*a + 16*r + w)] = v[slot16(r)];
    __syncthreads();
    #pragma unroll
    for (int q=0;q<16;q++) v[q] = lds[lxs(256*q + t)];
    if (j) twiddle<16>(v, TWO_PI*(float)j*(1.0f/65536.0f));
    fft16r<1>(v);
    float tvx[8], tvy[8];
    #pragma unroll
    for (int r=0;r<8;r++){
        int ts = j + 4096*r;
        float2 val = v[slot16(r)];
        U2[boff + ts] = val;
        tvx[r] = val.x; tvy[r] = val.y;
    }
    #pragma unroll
    for (int s=0;s<2;s++){
        int b = 2*pr + s;
        float rm[8];
        #pragma unroll
        for (int r=0;r<8;r++) rm[r] = rmA[b*8+r];
        float2 vv[16];
        #pragma unroll
        for (int r=0;r<8;r++){
            int n = j + 4096*r;
            float iv = 0.f;
            #pragma unroll
            for (int q=0;q<8;q++) iv += rm[q]*IR[(size_t)q*NSAMP + n];
            vv[r] = make_float2(s ? tvy[r] : tvx[r], iv);
        }
        #pragma unroll
        for (int r=8;r<16;r++) vv[r] = make_float2(0.f,0.f);
        __syncthreads();
        n1_tail<-1>(vv, lds, t, p, dstA + (size_t)b*NPAD);
    }
}

// Hermitian-pair product + stages (Ns=1,16) — wet chain (2 batch-pairs).
__global__ __launch_bounds__(256) void mfk_prod_f01(const float2* __restrict__ Z,
        float2* __restrict__ dst)
{
    __shared__ float2 lds[4096];
    int t = threadIdx.x;
    int px = blockIdx.x;
    int p = (px < 8) ? px : 23 - px;
    int pr = blockIdx.y;
    const float2* z0 = Z + (size_t)(2*pr)*NPAD;
    const float2* z1 = z0 + NPAD;
    int j = 256*(t>>4) + 16*p + (t&15);
    float2 v[16];
    #pragma unroll
    for (int r=0;r<16;r++){
        int k = j + 4096*r;
        int km = (NPAD - k) & (NPAD-1);
        float2 a = z0[k], am = z0[km];
        float2 A0 = make_float2(0.5f*(a.x+am.x), 0.5f*(a.y-am.y));
        float2 R0 = make_float2(0.5f*(a.y+am.y), -0.5f*(a.x-am.x));
        float2 P0 = cxmul(A0,R0);
        float2 b = z1[k], bm = z1[km];
        float2 A1 = make_float2(0.5f*(b.x+bm.x), 0.5f*(b.y-bm.y));
        float2 R1 = make_float2(0.5f*(b.y+bm.y), -0.5f*(b.x-bm.x));
        float2 P1 = cxmul(A1,R1);
        const float s = 1.0f/65536.0f;
        v[r] = make_float2((P0.x - P1.y)*s, (P0.y + P1.x)*s);
    }
    n1_tail<1>(v, lds, t, p, dst + (size_t)pr*NPAD);
}

// wet chain last pair: stages (256,4096) + final mix (dry from U2), writes out
__global__ __launch_bounds__(256) void mfk_f23_final(const float2* __restrict__ src,
        const float2* __restrict__ U2, const float* __restrict__ mxA,
        float* __restrict__ out)
{
    __shared__ float2 lds[4096];
    int t = threadIdx.x, p = blockIdx.x;
    int pr = blockIdx.y;
    size_t boff = (size_t)pr * NPAD;
    int a = t>>4, w = t&15;
    int j = 256*a + 16*p + w;
    const float2* x = src + boff;
    float2 v[16];
    #pragma unroll
    for (int r=0;r<16;r++) v[r] = x[j + 4096*r];
    int jm = 16*p + w;
    if (jm) twiddle<16>(v, TWO_PI*(float)jm*(1.0f/4096.0f));
    fft16r<1>(v);
    #pragma unroll
    for (int r=0;r<16;r++) lds[lxs(256*a + 16*r + w)] = v[slot16(r)];
    __syncthreads();
    #pragma unroll
    for (int q=0;q<16;q++) v[q] = lds[lxs(256*q + t)];
    if (j) twiddle<16>(v, TWO_PI*(float)j*(1.0f/65536.0f));
    fft16r<1>(v);
    int b0 = 2*pr, b1 = b0+1;
    float mx0 = mxA[b0], mx1 = mxA[b1];
    const float2* Ub = U2 + (size_t)pr*NPAD;
    #pragma unroll
    for (int r=0;r<8;r++){
        int ts = j + 4096*r;
        float2 val = v[slot16(r)];
        float2 dry = Ub[ts];
        out[(size_t)b0*NSAMP+ts] = dry.x*(1.f-mx0) + val.x*mx0;
        out[(size_t)b1*NSAMP+ts] = dry.y*(1.f-mx1) + val.y*mx1;
    }
}

extern "C" void kernel_launch(void* const* d_in, const int* in_sizes, int n_in,
                              void* d_out, int out_size, void* d_ws, size_t ws_size,
                              hipStream_t stream)
{
    (void)in_sizes; (void)n_in; (void)out_size;
    const float* EP   = (const float*)d_in[0];
    const float* MXR  = (const float*)d_in[1];
    const float* RL   = (const float*)d_in[2];
    const float* NOISE= (const float*)d_in[3];
    const float* IR   = (const float*)d_in[4];
    float* out = (float*)d_out;
    char* w = (char*)d_ws;

    auto need = [](long long g)->long long {
        return 2LL*g*NPAD*8 + 1LL*g*NSAMP*4 + (long long)NSAMP*8
             + 2048LL*128*4 + (128LL*8 + 2048 + 2048 + 4 + 32)*4
             + 4LL*NPAD*8 /*T*/ + 2LL*NPAD*8 /*U2*/ + 16384;
    };
    // G=64 keeps both arenas + tables inside the 256 MB Infinity Cache.
    int G = 64;
    while (G > 4 && need(G) > (long long)ws_size) G >>= 1;

    size_t off = 0;
    auto alloc = [&](size_t bytes)->char* {
        char* p = w + off; off += (bytes + 255) & ~(size_t)255; return p;
    };
    float2*   arA    = (float2*)alloc((size_t)G*NPAD*8);
    float2*   arB    = (float2*)alloc((size_t)G*NPAD*8);
    float*    locraw = (float*) alloc((size_t)G*NSAMP*4);
    float2*   T      = (float2*)alloc(4LL*NPAD*8);   // [z][beta] partial spectra
    float2*   U2     = (float2*)alloc(2LL*NPAD*8);   // packed located per batch-pair
    float2*   nspec  = (float2*)alloc((size_t)NSAMP*8);
    float*    cum    = (float*) alloc(2048LL*128*4); // transposed [jj][q]
    float*    chP    = (float*) alloc(128*8*4);
    unsigned* chQ    = (unsigned*)alloc(2048*4);
    float*    chR    = (float*) alloc(2048*4);
    float*    mxA    = (float*) alloc(4*4);
    float*    rmA    = (float*) alloc(32*4);

    // noise N1 (blocks 0..7) + full setup (blocks 8..15)
    mfk_n1_noise_setup<<<dim3(16),256,0,stream>>>(NOISE, arB, EP, MXR, RL,
                                                  chP, chQ, chR, cum, mxA, rmA);
    mfk_n2_noise<<<dim3(8),256,0,stream>>>(arB, nspec);

    for (int g0 = 0; g0 < NCH; g0 += G){
        int P = G/2;
        mfk_n1_specwin<<<dim3(8,P),256,0,stream>>>(nspec, chP, arA, g0);
        mfk_n2_unpack<<<dim3(8,P),256,0,stream>>>(arA, chP, locraw, g0);
        mfk_packZres_f01<<<dim3(16,G),256,0,stream>>>(locraw, chQ, chR, cum, arA, g0);
        mfk_f23<-1,16><<<dim3(16,G),256,0,stream>>>(arA, arB);
        mfk_prodacc<<<dim3(256,2,2),256,0,stream>>>(arB, T, g0, G, (g0>0)?1:0);
    }

    // single packed inverse (2 batch-pairs) fused with drypack + wet stage A
    mfk_plain_f01<<<dim3(16,2),256,0,stream>>>(T, arB);
    mfk_f23U2_dry<<<dim3(16,2),256,0,stream>>>(arB, rmA, IR, U2, arA);
    mfk_f23<-1,16><<<dim3(16,4),256,0,stream>>>(arA, arB);
    mfk_prod_f01<<<dim3(16,2),256,0,stream>>>(arB, arA);
    mfk_f23_final<<<dim3(16,2),256,0,stream>>>(arA, U2, mxA, out);
}

// Round 13
// 203.884 us; speedup vs baseline: 1.0215x; 1.0215x over previous
//
#include <hip/hip_runtime.h>
#include <math.h>

#define NSAMP 32768
#define NPAD  65536
#define NCH   128
#define TWO_PI 6.2831853071795864f
#define MINF ((float)(20.0/11025.0))
#define DRF  ((float)(4000.0/11025.0 - 20.0/11025.0))

__device__ __forceinline__ float2 cxmul(float2 a, float2 b){
    return make_float2(a.x*b.x - a.y*b.y, a.x*b.y + a.y*b.x);
}

template<int DIR>
__device__ __forceinline__ void fft4v(float2* v, int i0, int i1, int i2, int i3){
    float2 a=v[i0], b=v[i1], c=v[i2], d=v[i3];
    float2 t0 = make_float2(a.x+c.x, a.y+c.y);
    float2 t1 = make_float2(a.x-c.x, a.y-c.y);
    float2 t2 = make_float2(b.x+d.x, b.y+d.y);
    float2 t3 = make_float2(b.x-d.x, b.y-d.y);
    v[i0] = make_float2(t0.x+t2.x, t0.y+t2.y);
    v[i2] = make_float2(t0.x-t2.x, t0.y-t2.y);
    if (DIR < 0) {
        v[i1] = make_float2(t1.x + t3.y, t1.y - t3.x);
        v[i3] = make_float2(t1.x - t3.y, t1.y + t3.x);
    } else {
        v[i1] = make_float2(t1.x - t3.y, t1.y + t3.x);
        v[i3] = make_float2(t1.x + t3.y, t1.y - t3.x);
    }
}

template<int DIR>
__device__ __forceinline__ void twm(float2& v, float c, float s){
    float sy = (DIR<0) ? -s : s;
    v = cxmul(v, make_float2(c, sy));
}

template<int DIR>
__device__ __forceinline__ void fft16r(float2* v){
    const float C1=0.92387953251128674f, S1=0.38268343236508978f, H=0.70710678118654752f;
    fft4v<DIR>(v,0,4,8,12);
    fft4v<DIR>(v,1,5,9,13);
    fft4v<DIR>(v,2,6,10,14);
    fft4v<DIR>(v,3,7,11,15);
    twm<DIR>(v[5],  C1, S1);
    twm<DIR>(v[6],  H,  H);
    twm<DIR>(v[7],  S1, C1);
    twm<DIR>(v[9],  H,  H);
    twm<DIR>(v[10], 0.0f, 1.0f);
    twm<DIR>(v[11], -H, H);
    twm<DIR>(v[13], S1, C1);
    twm<DIR>(v[14], -H, H);
    twm<DIR>(v[15], -C1, -S1);
    fft4v<DIR>(v,0,1,2,3);
    fft4v<DIR>(v,4,5,6,7);
    fft4v<DIR>(v,8,9,10,11);
    fft4v<DIR>(v,12,13,14,15);
    // X[r] at slot ((r&3)<<2)|(r>>2)
}

template<int DIR>
__device__ __forceinline__ void fft8r(float2* v){
    const float H=0.70710678118654752f;
    #pragma unroll
    for (int n1=0;n1<4;n1++){
        float2 t=v[n1], u=v[n1+4];
        v[n1]   = make_float2(t.x+u.x, t.y+u.y);
        v[n1+4] = make_float2(t.x-u.x, t.y-u.y);
    }
    twm<DIR>(v[5], H, H);
    twm<DIR>(v[6], 0.0f, 1.0f);
    twm<DIR>(v[7], -H, H);
    fft4v<DIR>(v,0,1,2,3);
    fft4v<DIR>(v,4,5,6,7);
    // X[r] at slot ((r&1)<<2)|(r>>1)
}

__device__ __forceinline__ int slot16(int r){ return ((r&3)<<2)|(r>>2); }
__device__ __forceinline__ int slot8(int r){ return ((r&1)<<2)|(r>>1); }
// XOR swizzle: same bank spread as +pad, LDS stays exactly 4096 float2 (32 KB).
__device__ __forceinline__ int lxs(int l){ return l ^ ((l>>4)&15); }

// twiddle powers: 1 sincos + log-depth complex-power recurrence
template<int R>
__device__ __forceinline__ void twiddle(float2* v, float ang1){
    float s,c; __sincosf(ang1,&s,&c);
    float2 w[R];
    w[1] = make_float2(c,s);
    #pragma unroll
    for (int r=2;r<R;r++) w[r] = cxmul(w[r>>1], w[r-(r>>1)]);
    #pragma unroll
    for (int r=1;r<R;r++) v[r] = cxmul(v[r], w[r]);
}

// Double-stage tail for (Ns=1, Ns=16): stage A (no twiddle) -> LDS -> stage B -> store.
template<int DIR>
__device__ __forceinline__ void n1_tail(float2 (&v)[16], float2* lds, int t, int p,
                                        float2* __restrict__ out)
{
    fft16r<DIR>(v);
    #pragma unroll
    for (int r=0;r<16;r++) lds[lxs(256*(t>>4) + 16*(t&15) + r)] = v[slot16(r)];
    __syncthreads();
    #pragma unroll
    for (int q=0;q<16;q++) v[q] = lds[lxs(256*q + t)];
    int jm = t & 15;
    if (jm) twiddle<16>(v, (DIR<0?-TWO_PI:TWO_PI)*(float)jm*(1.0f/256.0f));
    fft16r<DIR>(v);
    int j2 = 256*p + t;
    float2* yo = out + (j2>>4)*256 + (j2&15);
    #pragma unroll
    for (int r=0;r<16;r++) yo[16*r] = v[slot16(r)];
}

// ---------------- N1 noise + full parameter setup (blocks 8..15) ----------------
// cum stored TRANSPOSED: cum[jj*2048 + q]  (coalesced writes and loads)
__global__ __launch_bounds__(256) void mfk_n1_noise_setup(const float* __restrict__ noise,
        float2* __restrict__ dst, const float* __restrict__ EP,
        const float* __restrict__ MXR, const float* __restrict__ RL,
        float* __restrict__ chP, unsigned* __restrict__ chQ, float* __restrict__ chR,
        float* __restrict__ cum, float* __restrict__ mxA, float* __restrict__ rmA)
{
    __shared__ float2 lds[4096];
    int t = threadIdx.x, px = blockIdx.x;
    if (px >= 8){
        int q = (px-8)*256 + t;          // chain id 0..2047
        int c = q >> 4, h = q & 15;
        const float* P = EP + c*22;
        const float LSQ = (float)0.9189385332046727;
        float f0m = __fmul_rn(P[4],P[4]);
        float f0s = __fadd_rn(MINF, __fmul_rn(f0m, DRF));
        float fr  = __fmul_rn(f0s, (float)(h+1));
        if (fr >= 1.0f) fr = 0.0f;
        chQ[q] = (unsigned)(unsigned long long)((double)fr*4294967296.0 + 0.5);
        float rs = __fadd_rn(__fmul_rn(P[6+h],0.2f),0.8f);
        chR[q] = rs;
        float cp = rs;
        for (int jj=0;jj<128;jj++){ cum[(size_t)jj*2048 + q] = cp; cp = __fmul_rn(cp, rs); }
        if (h == 0){
            float fm  = __fmul_rn(P[0],P[0]);
            float fmu = __fadd_rn(MINF, __fmul_rn(fm, DRF));
            float fsg = 1e-8f + P[1]*0.1f;
            float fsi = 1.0f/fsg;
            int i0 = (int)floorf(fmu*16384.0f + 0.5f);
            i0 = min(max(i0,0),16384);
            float rg = (float)i0 * (1.0f/16384.0f);
            float tt = (rg - fmu)*fsi;
            float Lc = logf(fsg) + LSQ;
            float sc = expf(-Lc) / (expf(-0.5f*tt*tt - Lc) + 1e-8f);
            float tmu = P[2];
            float tsg = 1e-8f + P[3]*0.1f;
            float tsi = 1.0f/tsg;
            int i1 = (int)floorf(tmu*32767.0f + 0.5f);
            i1 = min(max(i1,0),32767);
            float rg1 = (float)((double)i1 * (1.0/32767.0));
            float tt1 = (rg1 - tmu)*tsi;
            float Lc1 = logf(tsg) + LSQ;
            float sc1 = expf(-Lc1) / (expf(-0.5f*tt1*tt1 - Lc1) + 1e-8f);
            float amp = P[5]*P[5];
            float* o = chP + c*8;
            o[0]=fmu; o[1]=fsi; o[2]=sc; o[3]=tmu; o[4]=tsi; o[5]=sc1; o[6]=amp; o[7]=0.f;
        }
        if (q < 4){
            int b = q;
            mxA[b] = 1.0f/(1.0f + expf(-MXR[b]));
            const float* rl = RL + b*8;
            float mx = rl[0];
            for (int r=1;r<8;r++) mx = fmaxf(mx, rl[r]);
            float sum=0.f;
            float e2[8];
            for (int r=0;r<8;r++){ e2[r]=expf(rl[r]-mx); sum+=e2[r]; }
            for (int r=0;r<8;r++) rmA[b*8+r] = e2[r]/sum;
        }
        return;
    }
    int p = px;
    int j = 128*(t>>4) + 16*p + (t&15);
    float2 v[16];
    #pragma unroll
    for (int r=0;r<16;r++) v[r] = make_float2(noise[j + 2048*r], 0.0f);
    n1_tail<-1>(v, lds, t, p, dst);
}

__global__ __launch_bounds__(256) void mfk_n1_specwin(const float2* __restrict__ nspec,
        const float* __restrict__ chP, float2* __restrict__ dst, int g0)
{
    __shared__ float2 lds[4096];
    int t = threadIdx.x, p = blockIdx.x, pr = blockIdx.y;
    int c0 = g0 + 2*pr;
    const float* A = chP + c0*8;
    const float* B = chP + (c0+1)*8;
    float a0=A[0], a1=A[1], a2=A[2], b0=B[0], b1=B[1], b2=B[2];
    int j = 128*(t>>4) + 16*p + (t&15);
    float2 v[16];
    #pragma unroll
    for (int r=0;r<16;r++){
        int k = j + 2048*r;
        int kw = (k <= 16384) ? k : (32768 - k);
        float rg = (float)kw * (1.0f/16384.0f);
        float t0 = (rg - a0)*a1;
        float w0 = expf(-0.5f*t0*t0)*a2;
        float t1 = (rg - b0)*b1;
        float w1 = expf(-0.5f*t1*t1)*b2;
        float2 N = nspec[k];
        v[r] = make_float2(N.x*w0 - N.y*w1, N.y*w0 + N.x*w1);
    }
    n1_tail<1>(v, lds, t, p, dst + (size_t)pr*NSAMP);
}

// N2: stages (Ns=256 R16, Ns=4096 R8). Stage C: j2 = 256*(t>>5)+32p+(t&31).
template<int DIR>
__device__ __forceinline__ void n2_stageC(const float2* __restrict__ x, float2* lds, int t, int p)
{
    float2 v[16];
    int j2 = 256*(t>>5) + 32*p + (t&31);
    #pragma unroll
    for (int r=0;r<16;r++) v[r] = x[j2 + 2048*r];
    int jm = 32*p + (t&31);
    if (jm) twiddle<16>(v, (DIR<0?-TWO_PI:TWO_PI)*(float)jm*(1.0f/4096.0f));
    fft16r<DIR>(v);
    #pragma unroll
    for (int r=0;r<16;r++) lds[lxs(256*r + t)] = v[slot16(r)];
    __syncthreads();
}

template<int DIR>
__device__ __forceinline__ int n2_stageD(float2* lds, int t, int p, int u, float2 (&w8)[8])
{
    int q = t + 256*u;
    int j3 = ((q>>5)<<8) + 32*p + (q&31);
    #pragma unroll
    for (int r3=0;r3<8;r3++) w8[r3] = lds[lxs(256*(q>>5) + 32*r3 + (q&31))];
    if (j3) twiddle<8>(w8, (DIR<0?-TWO_PI:TWO_PI)*(float)j3*(1.0f/32768.0f));
    fft8r<DIR>(w8);
    return j3;
}

__global__ __launch_bounds__(256) void mfk_n2_noise(const float2* __restrict__ src,
                                                    float2* __restrict__ dst)
{
    __shared__ float2 lds[4096];
    int t = threadIdx.x, p = blockIdx.x;
    n2_stageC<-1>(src, lds, t, p);
    #pragma unroll
    for (int u=0;u<2;u++){
        float2 w8[8];
        int j3 = n2_stageD<-1>(lds, t, p, u, w8);
        #pragma unroll
        for (int r=0;r<8;r++) dst[j3 + 4096*r] = w8[slot8(r)];
    }
}

__global__ __launch_bounds__(256) void mfk_n2_unpack(const float2* __restrict__ src,
        const float* __restrict__ chP, float* __restrict__ locraw, int g0)
{
    __shared__ float2 lds[4096];
    int t = threadIdx.x, p = blockIdx.x, pr = blockIdx.y;
    n2_stageC<1>(src + (size_t)pr*NSAMP, lds, t, p);
    int lc0 = 2*pr;
    const float* C0 = chP + (g0+lc0)*8;
    const float* C1 = chP + (g0+lc0+1)*8;
    float c03=C0[3], c04=C0[4], c05=C0[5], c06=C0[6];
    float c13=C1[3], c14=C1[4], c15=C1[5], c16=C1[6];
    #pragma unroll
    for (int u=0;u<2;u++){
        float2 w8[8];
        int j3 = n2_stageD<1>(lds, t, p, u, w8);
        #pragma unroll
        for (int r=0;r<8;r++){
            int n = j3 + 4096*r;
            float2 val = w8[slot8(r)];
            float rg = (float)((double)n * (1.0/32767.0));
            float tt0 = (rg - c03)*c04;
            float ew0 = expf(-0.5f*tt0*tt0)*c05;
            float tt1 = (rg - c13)*c14;
            float ew1 = expf(-0.5f*tt1*tt1)*c15;
            locraw[(size_t)lc0*NSAMP + n]     = val.x*(1.0f/32768.0f)*ew0*c06;
            locraw[(size_t)(lc0+1)*NSAMP + n] = val.y*(1.0f/32768.0f)*ew1*c16;
        }
    }
}

// ---------------- NPAD kernels ----------------
// packZ + in-register resonance synthesis + stages (Ns=1,16) of 65536-FFT.
// cum table: transposed global [jj][q], LDS [jj][hh]; qS/rS union'd into lds (32 KB total).
__global__ __launch_bounds__(256) void mfk_packZres_f01(const float* __restrict__ locraw,
        const unsigned* __restrict__ chQ, const float* __restrict__ chR,
        const float* __restrict__ cum, float2* __restrict__ dst, int g0)
{
    __shared__ float2 lds[4096];
    float* cumS = (float*)lds;                      // floats [0,2048): [jj][hh]
    unsigned* qS = (unsigned*)(cumS + 2048);        // floats [2048,2064)
    float* rS = cumS + 2064;                        // floats [2064,2080)
    int t = threadIdx.x, p = blockIdx.x, lc = blockIdx.y;
    int cg = g0 + lc;
    #pragma unroll
    for (int i=0;i<8;i++){
        int jj = (t>>4) + 16*i;
        cumS[jj*16 + (t&15)] = cum[(size_t)jj*2048 + cg*16 + (t&15)];
    }
    if (t < 16){ qS[t] = chQ[cg*16 + t]; rS[t] = chR[cg*16 + t]; }
    __syncthreads();
    int j = 256*(t>>4) + 16*p + (t&15);
    // co advances by exactly +16 per r-step; wf r-invariant. ilo in {-1, 0..15}.
    float co0 = ((float)j + 0.5f)*0.00390625f - 0.5f;
    float fl = floorf(co0);
    float wf = co0 - fl;
    int ilo = (int)fl;
    float acc[8];
    #pragma unroll
    for (int r=0;r<8;r++) acc[r] = 0.0f;
    if (j == 0) acc[0] = 1.0f;   // +delta carries the residual "+located" through conv
    unsigned T1 = (unsigned)(j+1);
    #pragma unroll
    for (int hh=0; hh<16; hh++){
        unsigned qq = qS[hh];
        float rs = rS[hh];
        float rs2 = rs*rs, rs4 = rs2*rs2, rs8 = rs4*rs4, rs16 = rs8*rs8;
        float mix = fmaf(rs - 1.0f, wf, 1.0f);
        unsigned bits = qq * T1;
        unsigned step = qq << 12;
        float e_cur = (ilo >= 0) ? cumS[ilo*16 + hh] : cumS[15*16 + hh];
        float env0  = (ilo >= 0) ? 0.0f : cumS[hh];   // only used when ilo<0, r=0
        #pragma unroll
        for (int r=0;r<8;r++){
            float env;
            if (r == 0 && ilo < 0) env = env0;                       // low clamp: wf=0
            else env = (ilo == 15 && r == 7) ? e_cur : e_cur*mix;    // high clamp at lo=127
            float m = (float)bits * 2.3283064365386963e-10f;
            float sv; asm("v_sin_f32 %0, %1" : "=v"(sv) : "v"(m));
            acc[r] = fmaf(env, sv, acc[r]);
            bits += step;
            if (!(r == 0 && ilo < 0)) e_cur *= rs16;
        }
    }
    const float* la = locraw + (size_t)lc*NSAMP;
    float2 v[16];
    #pragma unroll
    for (int r=0;r<8;r++) v[r] = make_float2(la[j + 4096*r], acc[r]);
    #pragma unroll
    for (int r=8;r<16;r++) v[r] = make_float2(0.f,0.f);
    __syncthreads();                       // cumS/qS/rS reads done before lds reuse
    n1_tail<-1>(v, lds, t, p, dst + (size_t)lc*NPAD);
}

// stages (Ns=256, 4096) of 65536-FFT; NSTORE=8 skips discarded upper half.
template<int DIR, int NSTORE>
__global__ __launch_bounds__(256) void mfk_f23(const float2* __restrict__ src,
                                               float2* __restrict__ dst)
{
    __shared__ float2 lds[4096];
    int t = threadIdx.x, p = blockIdx.x;
    size_t boff = (size_t)blockIdx.y * NPAD;
    int a = t>>4, w = t&15;
    int j = 256*a + 16*p + w;
    const float2* x = src + boff;
    float2 v[16];
    #pragma unroll
    for (int r=0;r<16;r++) v[r] = x[j + 4096*r];
    int jm = 16*p + w;
    if (jm) twiddle<16>(v, (DIR<0?-TWO_PI:TWO_PI)*(float)jm*(1.0f/4096.0f));
    fft16r<DIR>(v);
    #pragma unroll
    for (int r=0;r<16;r++) lds[lxs(256*a + 16*r + w)] = v[slot16(r)];
    __syncthreads();
    #pragma unroll
    for (int q=0;q<16;q++) v[q] = lds[lxs(256*q + t)];
    if (j) twiddle<16>(v, (DIR<0?-TWO_PI:TWO_PI)*(float)j*(1.0f/65536.0f));
    fft16r<DIR>(v);
    float2* yo = dst + boff + j;
    #pragma unroll
    for (int r=0;r<NSTORE;r++) yo[4096*r] = v[slot16(r)];
}

// ---------------- spectral product + event-sum (linearity) ----------------
// S_b[k] = sum_e A_e[k]*R_e[k]; batches packed: T = S_{2beta} + i*S_{2beta+1}.
// grid (256, 2 beta, 2 z-half); mirror-paired blocks share an XCD (x ^ 8).
__global__ __launch_bounds__(256) void mfk_prodacc(const float2* __restrict__ Z,
        float2* __restrict__ T, int g0, int G, int addTo)
{
    int x = blockIdx.x;
    int beta = blockIdx.y;
    int z = blockIdx.z;
    int g = ((x>>4)<<3) | (x&7);
    int kb = (x&8) ? (255 - g) : g;
    int k = kb*256 + threadIdx.x;
    int km = (NPAD - k) & (NPAD-1);
    int cstart = max(64*beta + 32*z, g0);
    int cend   = min(64*beta + 32*z + 32, g0+G);
    float2 S0 = make_float2(0.f,0.f), S1 = make_float2(0.f,0.f);
    #pragma unroll 4
    for (int c=cstart; c<cend; ++c){
        const float2* zp = Z + (size_t)(c-g0)*NPAD;
        float2 a = zp[k], am = zp[km];
        float2 A0 = make_float2(0.5f*(a.x+am.x), 0.5f*(a.y-am.y));
        float2 R0 = make_float2(0.5f*(a.y+am.y), -0.5f*(a.x-am.x));
        float2 P = cxmul(A0,R0);
        if ((c>>5)&1){ S1.x += P.x; S1.y += P.y; }
        else         { S0.x += P.x; S0.y += P.y; }
    }
    const float s = 1.0f/65536.0f;
    float2 q = make_float2((S0.x - S1.y)*s, (S0.y + S1.x)*s);
    size_t idx = ((size_t)z*2 + beta)*NPAD + k;
    if (addTo){ float2 o = T[idx]; q.x += o.x; q.y += o.y; }
    T[idx] = q;
}

// plain first inverse pair (Ns=1,16), summing the two z-half partial spectra
__global__ __launch_bounds__(256) void mfk_plain_f01(const float2* __restrict__ T,
        float2* __restrict__ dst)
{
    __shared__ float2 lds[4096];
    int t = threadIdx.x, p = blockIdx.x, b = blockIdx.y;
    const float2* x0 = T + (size_t)b*NPAD;
    const float2* x1 = T + (size_t)(2+b)*NPAD;
    int j = 256*(t>>4) + 16*p + (t&15);
    float2 v[16];
    #pragma unroll
    for (int r=0;r<16;r++){
        float2 u0 = x0[j + 4096*r], u1 = x1[j + 4096*r];
        v[r] = make_float2(u0.x+u1.x, u0.y+u1.y);
    }
    n1_tail<1>(v, lds, t, p, dst + (size_t)b*NPAD);
}

// FUSED: f23<1,8> (finishing located inverse FFT) -> store U2 -> drypack both
// batches of the pair -> two n1_tail stage-A passes of the wet forward FFT.
__global__ __launch_bounds__(256) void mfk_f23U2_dry(const float2* __restrict__ src,
        const float* __restrict__ rmA, const float* __restrict__ IR,
        float2* __restrict__ U2, float2* __restrict__ dstA)
{
    __shared__ float2 lds[4096];
    int t = threadIdx.x, p = blockIdx.x, pr = blockIdx.y;
    size_t boff = (size_t)pr * NPAD;
    int a = t>>4, w = t&15;
    int j = 256*a + 16*p + w;
    const float2* x = src + boff;
    float2 v[16];
    #pragma unroll
    for (int r=0;r<16;r++) v[r] = x[j + 4096*r];
    int jm = 16*p + w;
    if (jm) twiddle<16>(v, TWO_PI*(float)jm*(1.0f/4096.0f));
    fft16r<1>(v);
    #pragma unroll
    for (int r=0;r<16;r++) lds[lxs(256*a + 16*r + w)] = v[slot16(r)];
    __syncthreads();
    #pragma unroll
    for (int q=0;q<16;q++) v[q] = lds[lxs(256*q + t)];
    if (j) twiddle<16>(v, TWO_PI*(float)j*(1.0f/65536.0f));
    fft16r<1>(v);
    float tvx[8], tvy[8];
    #pragma unroll
    for (int r=0;r<8;r++){
        int ts = j + 4096*r;
        float2 val = v[slot16(r)];
        U2[boff + ts] = val;
        tvx[r] = val.x; tvy[r] = val.y;
    }
    #pragma unroll
    for (int s=0;s<2;s++){
        int b = 2*pr + s;
        float rm[8];
        #pragma unroll
        for (int r=0;r<8;r++) rm[r] = rmA[b*8+r];
        float2 vv[16];
        #pragma unroll
        for (int r=0;r<8;r++){
            int n = j + 4096*r;
            float iv = 0.f;
            #pragma unroll
            for (int q=0;q<8;q++) iv += rm[q]*IR[(size_t)q*NSAMP + n];
            vv[r] = make_float2(s ? tvy[r] : tvx[r], iv);
        }
        #pragma unroll
        for (int r=8;r<16;r++) vv[r] = make_float2(0.f,0.f);
        __syncthreads();
        n1_tail<-1>(vv, lds, t, p, dstA + (size_t)b*NPAD);
    }
}

// Hermitian-pair product + stages (Ns=1,16) — wet chain (2 batch-pairs).
__global__ __launch_bounds__(256) void mfk_prod_f01(const float2* __restrict__ Z,
        float2* __restrict__ dst)
{
    __shared__ float2 lds[4096];
    int t = threadIdx.x;
    int px = blockIdx.x;
    int p = (px < 8) ? px : 23 - px;
    int pr = blockIdx.y;
    const float2* z0 = Z + (size_t)(2*pr)*NPAD;
    const float2* z1 = z0 + NPAD;
    int j = 256*(t>>4) + 16*p + (t&15);
    float2 v[16];
    #pragma unroll
    for (int r=0;r<16;r++){
        int k = j + 4096*r;
        int km = (NPAD - k) & (NPAD-1);
        float2 a = z0[k], am = z0[km];
        float2 A0 = make_float2(0.5f*(a.x+am.x), 0.5f*(a.y-am.y));
        float2 R0 = make_float2(0.5f*(a.y+am.y), -0.5f*(a.x-am.x));
        float2 P0 = cxmul(A0,R0);
        float2 b = z1[k], bm = z1[km];
        float2 A1 = make_float2(0.5f*(b.x+bm.x), 0.5f*(b.y-bm.y));
        float2 R1 = make_float2(0.5f*(b.y+bm.y), -0.5f*(b.x-bm.x));
        float2 P1 = cxmul(A1,R1);
        const float s = 1.0f/65536.0f;
        v[r] = make_float2((P0.x - P1.y)*s, (P0.y + P1.x)*s);
    }
    n1_tail<1>(v, lds, t, p, dst + (size_t)pr*NPAD);
}

// wet chain last pair: stages (256,4096) + final mix (dry from U2), writes out
__global__ __launch_bounds__(256) void mfk_f23_final(const float2* __restrict__ src,
        const float2* __restrict__ U2, const float* __restrict__ mxA,
        float* __restrict__ out)
{
    __shared__ float2 lds[4096];
    int t = threadIdx.x, p = blockIdx.x;
    int pr = blockIdx.y;
    size_t boff = (size_t)pr * NPAD;
    int a = t>>4, w = t&15;
    int j = 256*a + 16*p + w;
    const float2* x = src + boff;
    float2 v[16];
    #pragma unroll
    for (int r=0;r<16;r++) v[r] = x[j + 4096*r];
    int jm = 16*p + w;
    if (jm) twiddle<16>(v, TWO_PI*(float)jm*(1.0f/4096.0f));
    fft16r<1>(v);
    #pragma unroll
    for (int r=0;r<16;r++) lds[lxs(256*a + 16*r + w)] = v[slot16(r)];
    __syncthreads();
    #pragma unroll
    for (int q=0;q<16;q++) v[q] = lds[lxs(256*q + t)];
    if (j) twiddle<16>(v, TWO_PI*(float)j*(1.0f/65536.0f));
    fft16r<1>(v);
    int b0 = 2*pr, b1 = b0+1;
    float mx0 = mxA[b0], mx1 = mxA[b1];
    const float2* Ub = U2 + (size_t)pr*NPAD;
    #pragma unroll
    for (int r=0;r<8;r++){
        int ts = j + 4096*r;
        float2 val = v[slot16(r)];
        float2 dry = Ub[ts];
        out[(size_t)b0*NSAMP+ts] = dry.x*(1.f-mx0) + val.x*mx0;
        out[(size_t)b1*NSAMP+ts] = dry.y*(1.f-mx1) + val.y*mx1;
    }
}

extern "C" void kernel_launch(void* const* d_in, const int* in_sizes, int n_in,
                              void* d_out, int out_size, void* d_ws, size_t ws_size,
                              hipStream_t stream)
{
    (void)in_sizes; (void)n_in; (void)out_size;
    const float* EP   = (const float*)d_in[0];
    const float* MXR  = (const float*)d_in[1];
    const float* RL   = (const float*)d_in[2];
    const float* NOISE= (const float*)d_in[3];
    const float* IR   = (const float*)d_in[4];
    float* out = (float*)d_out;
    char* w = (char*)d_ws;

    auto need = [](long long g)->long long {
        return 2LL*g*NPAD*8 + 1LL*g*NSAMP*4 + (long long)NSAMP*8
             + 2048LL*128*4 + (128LL*8 + 2048 + 2048 + 4 + 32)*4
             + 4LL*NPAD*8 /*T*/ + 2LL*NPAD*8 /*U2*/ + 16384;
    };
    // G=128: maximize per-launch parallelism (R12 showed G=64 regresses via
    // doubled launch count + grid-tail drain, despite better L3 residency).
    int G = 128;
    while (G > 4 && need(G) > (long long)ws_size) G >>= 1;

    size_t off = 0;
    auto alloc = [&](size_t bytes)->char* {
        char* p = w + off; off += (bytes + 255) & ~(size_t)255; return p;
    };
    float2*   arA    = (float2*)alloc((size_t)G*NPAD*8);
    float2*   arB    = (float2*)alloc((size_t)G*NPAD*8);
    float*    locraw = (float*) alloc((size_t)G*NSAMP*4);
    float2*   T      = (float2*)alloc(4LL*NPAD*8);   // [z][beta] partial spectra
    float2*   U2     = (float2*)alloc(2LL*NPAD*8);   // packed located per batch-pair
    float2*   nspec  = (float2*)alloc((size_t)NSAMP*8);
    float*    cum    = (float*) alloc(2048LL*128*4); // transposed [jj][q]
    float*    chP    = (float*) alloc(128*8*4);
    unsigned* chQ    = (unsigned*)alloc(2048*4);
    float*    chR    = (float*) alloc(2048*4);
    float*    mxA    = (float*) alloc(4*4);
    float*    rmA    = (float*) alloc(32*4);

    // noise N1 (blocks 0..7) + full setup (blocks 8..15)
    mfk_n1_noise_setup<<<dim3(16),256,0,stream>>>(NOISE, arB, EP, MXR, RL,
                                                  chP, chQ, chR, cum, mxA, rmA);
    mfk_n2_noise<<<dim3(8),256,0,stream>>>(arB, nspec);

    for (int g0 = 0; g0 < NCH; g0 += G){
        int P = G/2;
        mfk_n1_specwin<<<dim3(8,P),256,0,stream>>>(nspec, chP, arA, g0);
        mfk_n2_unpack<<<dim3(8,P),256,0,stream>>>(arA, chP, locraw, g0);
        mfk_packZres_f01<<<dim3(16,G),256,0,stream>>>(locraw, chQ, chR, cum, arA, g0);
        mfk_f23<-1,16><<<dim3(16,G),256,0,stream>>>(arA, arB);
        mfk_prodacc<<<dim3(256,2,2),256,0,stream>>>(arB, T, g0, G, (g0>0)?1:0);
    }

    // single packed inverse (2 batch-pairs) fused with drypack + wet stage A
    mfk_plain_f01<<<dim3(16,2),256,0,stream>>>(T, arB);
    mfk_f23U2_dry<<<dim3(16,2),256,0,stream>>>(arB, rmA, IR, U2, arA);
    mfk_f23<-1,16><<<dim3(16,4),256,0,stream>>>(arA, arB);
    mfk_prod_f01<<<dim3(16,2),256,0,stream>>>(arB, arA);
    mfk_f23_final<<<dim3(16,2),256,0,stream>>>(arA, U2, mxA, out);
}

// Round 14
// 176.221 us; speedup vs baseline: 1.1819x; 1.1570x over previous
//
#include <hip/hip_runtime.h>
#include <math.h>

#define NSAMP 32768
#define NPAD  65536
#define NCH   128
#define TWO_PI 6.2831853071795864f
#define MINF ((float)(20.0/11025.0))
#define DRF  ((float)(4000.0/11025.0 - 20.0/11025.0))

__device__ __forceinline__ float2 cxmul(float2 a, float2 b){
    return make_float2(a.x*b.x - a.y*b.y, a.x*b.y + a.y*b.x);
}

template<int DIR>
__device__ __forceinline__ void fft4v(float2* v, int i0, int i1, int i2, int i3){
    float2 a=v[i0], b=v[i1], c=v[i2], d=v[i3];
    float2 t0 = make_float2(a.x+c.x, a.y+c.y);
    float2 t1 = make_float2(a.x-c.x, a.y-c.y);
    float2 t2 = make_float2(b.x+d.x, b.y+d.y);
    float2 t3 = make_float2(b.x-d.x, b.y-d.y);
    v[i0] = make_float2(t0.x+t2.x, t0.y+t2.y);
    v[i2] = make_float2(t0.x-t2.x, t0.y-t2.y);
    if (DIR < 0) {
        v[i1] = make_float2(t1.x + t3.y, t1.y - t3.x);
        v[i3] = make_float2(t1.x - t3.y, t1.y + t3.x);
    } else {
        v[i1] = make_float2(t1.x - t3.y, t1.y + t3.x);
        v[i3] = make_float2(t1.x + t3.y, t1.y - t3.x);
    }
}

template<int DIR>
__device__ __forceinline__ void twm(float2& v, float c, float s){
    float sy = (DIR<0) ? -s : s;
    v = cxmul(v, make_float2(c, sy));
}

template<int DIR>
__device__ __forceinline__ void fft16r(float2* v){
    const float C1=0.92387953251128674f, S1=0.38268343236508978f, H=0.70710678118654752f;
    fft4v<DIR>(v,0,4,8,12);
    fft4v<DIR>(v,1,5,9,13);
    fft4v<DIR>(v,2,6,10,14);
    fft4v<DIR>(v,3,7,11,15);
    twm<DIR>(v[5],  C1, S1);
    twm<DIR>(v[6],  H,  H);
    twm<DIR>(v[7],  S1, C1);
    twm<DIR>(v[9],  H,  H);
    twm<DIR>(v[10], 0.0f, 1.0f);
    twm<DIR>(v[11], -H, H);
    twm<DIR>(v[13], S1, C1);
    twm<DIR>(v[14], -H, H);
    twm<DIR>(v[15], -C1, -S1);
    fft4v<DIR>(v,0,1,2,3);
    fft4v<DIR>(v,4,5,6,7);
    fft4v<DIR>(v,8,9,10,11);
    fft4v<DIR>(v,12,13,14,15);
    // X[r] at slot ((r&3)<<2)|(r>>2)
}

template<int DIR>
__device__ __forceinline__ void fft8r(float2* v){
    const float H=0.70710678118654752f;
    #pragma unroll
    for (int n1=0;n1<4;n1++){
        float2 t=v[n1], u=v[n1+4];
        v[n1]   = make_float2(t.x+u.x, t.y+u.y);
        v[n1+4] = make_float2(t.x-u.x, t.y-u.y);
    }
    twm<DIR>(v[5], H, H);
    twm<DIR>(v[6], 0.0f, 1.0f);
    twm<DIR>(v[7], -H, H);
    fft4v<DIR>(v,0,1,2,3);
    fft4v<DIR>(v,4,5,6,7);
    // X[r] at slot ((r&1)<<2)|(r>>1)
}

__device__ __forceinline__ int slot16(int r){ return ((r&3)<<2)|(r>>2); }
__device__ __forceinline__ int slot8(int r){ return ((r&1)<<2)|(r>>1); }
// XOR swizzle: same bank spread as +pad, LDS stays exactly 4096 float2 (32 KB).
__device__ __forceinline__ int lxs(int l){ return l ^ ((l>>4)&15); }

// twiddle powers: 1 sincos + log-depth complex-power recurrence
template<int R>
__device__ __forceinline__ void twiddle(float2* v, float ang1){
    float s,c; __sincosf(ang1,&s,&c);
    float2 w[R];
    w[1] = make_float2(c,s);
    #pragma unroll
    for (int r=2;r<R;r++) w[r] = cxmul(w[r>>1], w[r-(r>>1)]);
    #pragma unroll
    for (int r=1;r<R;r++) v[r] = cxmul(v[r], w[r]);
}

// Double-stage tail for (Ns=1, Ns=16): stage A (no twiddle) -> LDS -> stage B -> store.
template<int DIR>
__device__ __forceinline__ void n1_tail(float2 (&v)[16], float2* lds, int t, int p,
                                        float2* __restrict__ out)
{
    fft16r<DIR>(v);
    #pragma unroll
    for (int r=0;r<16;r++) lds[lxs(256*(t>>4) + 16*(t&15) + r)] = v[slot16(r)];
    __syncthreads();
    #pragma unroll
    for (int q=0;q<16;q++) v[q] = lds[lxs(256*q + t)];
    int jm = t & 15;
    if (jm) twiddle<16>(v, (DIR<0?-TWO_PI:TWO_PI)*(float)jm*(1.0f/256.0f));
    fft16r<DIR>(v);
    int j2 = 256*p + t;
    float2* yo = out + (j2>>4)*256 + (j2&15);
    #pragma unroll
    for (int r=0;r<16;r++) yo[16*r] = v[slot16(r)];
}

// ---------------- N1 noise + full parameter setup (blocks 8..15) ----------------
__global__ __launch_bounds__(256) void mfk_n1_noise_setup(const float* __restrict__ noise,
        float2* __restrict__ dst, const float* __restrict__ EP,
        const float* __restrict__ MXR, const float* __restrict__ RL,
        float* __restrict__ chP, unsigned* __restrict__ chQ, float* __restrict__ chR,
        float* __restrict__ cum, float* __restrict__ mxA, float* __restrict__ rmA)
{
    __shared__ float2 lds[4096];
    int t = threadIdx.x, px = blockIdx.x;
    if (px >= 8){
        int q = (px-8)*256 + t;          // chain id 0..2047
        int c = q >> 4, h = q & 15;
        const float* P = EP + c*22;
        const float LSQ = (float)0.9189385332046727;
        float f0m = __fmul_rn(P[4],P[4]);
        float f0s = __fadd_rn(MINF, __fmul_rn(f0m, DRF));
        float fr  = __fmul_rn(f0s, (float)(h+1));
        if (fr >= 1.0f) fr = 0.0f;
        chQ[q] = (unsigned)(unsigned long long)((double)fr*4294967296.0 + 0.5);
        float rs = __fadd_rn(__fmul_rn(P[6+h],0.2f),0.8f);
        chR[q] = rs;
        float cp = rs;
        float* crow = cum + (size_t)q*128;
        for (int jj=0;jj<128;jj++){ crow[jj] = cp; cp = __fmul_rn(cp, rs); }
        if (h == 0){
            float fm  = __fmul_rn(P[0],P[0]);
            float fmu = __fadd_rn(MINF, __fmul_rn(fm, DRF));
            float fsg = 1e-8f + P[1]*0.1f;
            float fsi = 1.0f/fsg;
            int i0 = (int)floorf(fmu*16384.0f + 0.5f);
            i0 = min(max(i0,0),16384);
            float rg = (float)i0 * (1.0f/16384.0f);
            float tt = (rg - fmu)*fsi;
            float Lc = logf(fsg) + LSQ;
            float sc = expf(-Lc) / (expf(-0.5f*tt*tt - Lc) + 1e-8f);
            float tmu = P[2];
            float tsg = 1e-8f + P[3]*0.1f;
            float tsi = 1.0f/tsg;
            int i1 = (int)floorf(tmu*32767.0f + 0.5f);
            i1 = min(max(i1,0),32767);
            float rg1 = (float)((double)i1 * (1.0/32767.0));
            float tt1 = (rg1 - tmu)*tsi;
            float Lc1 = logf(tsg) + LSQ;
            float sc1 = expf(-Lc1) / (expf(-0.5f*tt1*tt1 - Lc1) + 1e-8f);
            float amp = P[5]*P[5];
            float* o = chP + c*8;
            o[0]=fmu; o[1]=fsi; o[2]=sc; o[3]=tmu; o[4]=tsi; o[5]=sc1; o[6]=amp; o[7]=0.f;
        }
        if (q < 4){
            int b = q;
            mxA[b] = 1.0f/(1.0f + expf(-MXR[b]));
            const float* rl = RL + b*8;
            float mx = rl[0];
            for (int r=1;r<8;r++) mx = fmaxf(mx, rl[r]);
            float sum=0.f;
            float e2[8];
            for (int r=0;r<8;r++){ e2[r]=expf(rl[r]-mx); sum+=e2[r]; }
            for (int r=0;r<8;r++) rmA[b*8+r] = e2[r]/sum;
        }
        return;
    }
    int p = px;
    int j = 128*(t>>4) + 16*p + (t&15);
    float2 v[16];
    #pragma unroll
    for (int r=0;r<16;r++) v[r] = make_float2(noise[j + 2048*r], 0.0f);
    n1_tail<-1>(v, lds, t, p, dst);
}

__global__ __launch_bounds__(256) void mfk_n1_specwin(const float2* __restrict__ nspec,
        const float* __restrict__ chP, float2* __restrict__ dst, int g0)
{
    __shared__ float2 lds[4096];
    int t = threadIdx.x, p = blockIdx.x, pr = blockIdx.y;
    int c0 = g0 + 2*pr;
    const float* A = chP + c0*8;
    const float* B = chP + (c0+1)*8;
    float a0=A[0], a1=A[1], a2=A[2], b0=B[0], b1=B[1], b2=B[2];
    int j = 128*(t>>4) + 16*p + (t&15);
    float2 v[16];
    #pragma unroll
    for (int r=0;r<16;r++){
        int k = j + 2048*r;
        int kw = (k <= 16384) ? k : (32768 - k);
        float rg = (float)kw * (1.0f/16384.0f);
        float t0 = (rg - a0)*a1;
        float w0 = expf(-0.5f*t0*t0)*a2;
        float t1 = (rg - b0)*b1;
        float w1 = expf(-0.5f*t1*t1)*b2;
        float2 N = nspec[k];
        v[r] = make_float2(N.x*w0 - N.y*w1, N.y*w0 + N.x*w1);
    }
    n1_tail<1>(v, lds, t, p, dst + (size_t)pr*NSAMP);
}

// N2: stages (Ns=256 R16, Ns=4096 R8). Stage C: j2 = 256*(t>>5)+32p+(t&31).
template<int DIR>
__device__ __forceinline__ void n2_stageC(const float2* __restrict__ x, float2* lds, int t, int p)
{
    float2 v[16];
    int j2 = 256*(t>>5) + 32*p + (t&31);
    #pragma unroll
    for (int r=0;r<16;r++) v[r] = x[j2 + 2048*r];
    int jm = 32*p + (t&31);
    if (jm) twiddle<16>(v, (DIR<0?-TWO_PI:TWO_PI)*(float)jm*(1.0f/4096.0f));
    fft16r<DIR>(v);
    #pragma unroll
    for (int r=0;r<16;r++) lds[lxs(256*r + t)] = v[slot16(r)];
    __syncthreads();
}

template<int DIR>
__device__ __forceinline__ int n2_stageD(float2* lds, int t, int p, int u, float2 (&w8)[8])
{
    int q = t + 256*u;
    int j3 = ((q>>5)<<8) + 32*p + (q&31);
    #pragma unroll
    for (int r3=0;r3<8;r3++) w8[r3] = lds[lxs(256*(q>>5) + 32*r3 + (q&31))];
    if (j3) twiddle<8>(w8, (DIR<0?-TWO_PI:TWO_PI)*(float)j3*(1.0f/32768.0f));
    fft8r<DIR>(w8);
    return j3;
}

__global__ __launch_bounds__(256) void mfk_n2_noise(const float2* __restrict__ src,
                                                    float2* __restrict__ dst)
{
    __shared__ float2 lds[4096];
    int t = threadIdx.x, p = blockIdx.x;
    n2_stageC<-1>(src, lds, t, p);
    #pragma unroll
    for (int u=0;u<2;u++){
        float2 w8[8];
        int j3 = n2_stageD<-1>(lds, t, p, u, w8);
        #pragma unroll
        for (int r=0;r<8;r++) dst[j3 + 4096*r] = w8[slot8(r)];
    }
}

__global__ __launch_bounds__(256) void mfk_n2_unpack(const float2* __restrict__ src,
        const float* __restrict__ chP, float* __restrict__ locraw, int g0)
{
    __shared__ float2 lds[4096];
    int t = threadIdx.x, p = blockIdx.x, pr = blockIdx.y;
    n2_stageC<1>(src + (size_t)pr*NSAMP, lds, t, p);
    int lc0 = 2*pr;
    const float* C0 = chP + (g0+lc0)*8;
    const float* C1 = chP + (g0+lc0+1)*8;
    float c03=C0[3], c04=C0[4], c05=C0[5], c06=C0[6];
    float c13=C1[3], c14=C1[4], c15=C1[5], c16=C1[6];
    #pragma unroll
    for (int u=0;u<2;u++){
        float2 w8[8];
        int j3 = n2_stageD<1>(lds, t, p, u, w8);
        #pragma unroll
        for (int r=0;r<8;r++){
            int n = j3 + 4096*r;
            float2 val = w8[slot8(r)];
            float rg = (float)((double)n * (1.0/32767.0));
            float tt0 = (rg - c03)*c04;
            float ew0 = expf(-0.5f*tt0*tt0)*c05;
            float tt1 = (rg - c13)*c14;
            float ew1 = expf(-0.5f*tt1*tt1)*c15;
            locraw[(size_t)lc0*NSAMP + n]     = val.x*(1.0f/32768.0f)*ew0*c06;
            locraw[(size_t)(lc0+1)*NSAMP + n] = val.y*(1.0f/32768.0f)*ew1*c16;
        }
    }
}

// ---------------- NPAD kernels ----------------
// packZ + in-register resonance synthesis + stages (Ns=1,16) of 65536-FFT.
// Envelope via multiplicative recurrence; qS/rS union'd into lds -> exactly 32 KB.
__global__ __launch_bounds__(256) void mfk_packZres_f01(const float* __restrict__ locraw,
        const unsigned* __restrict__ chQ, const float* __restrict__ chR,
        const float* __restrict__ cum, float2* __restrict__ dst, int g0)
{
    __shared__ float2 lds[4096];
    float* cumS = (float*)lds;                      // floats [0,2048): [hh][128]
    unsigned* qS = (unsigned*)(cumS + 2048);        // floats [2048,2064)
    float* rS = cumS + 2064;                        // floats [2064,2080)
    int t = threadIdx.x, p = blockIdx.x, lc = blockIdx.y;
    int cg = g0 + lc;
    const float* crow = cum + (size_t)cg*2048;
    #pragma unroll
    for (int i=0;i<8;i++) cumS[t + 256*i] = crow[t + 256*i];
    if (t < 16){ qS[t] = chQ[cg*16 + t]; rS[t] = chR[cg*16 + t]; }
    __syncthreads();
    int j = 256*(t>>4) + 16*p + (t&15);
    // co advances by exactly +16 per r-step; wf r-invariant. ilo in {-1, 0..15}.
    float co0 = ((float)j + 0.5f)*0.00390625f - 0.5f;
    float fl = floorf(co0);
    float wf = co0 - fl;
    int ilo = (int)fl;
    float acc[8];
    #pragma unroll
    for (int r=0;r<8;r++) acc[r] = 0.0f;
    if (j == 0) acc[0] = 1.0f;   // +delta carries the residual "+located" through conv
    unsigned T1 = (unsigned)(j+1);
    #pragma unroll
    for (int hh=0; hh<16; hh++){
        unsigned qq = qS[hh];
        float rs = rS[hh];
        float rs2 = rs*rs, rs4 = rs2*rs2, rs8 = rs4*rs4, rs16 = rs8*rs8;
        float mix = fmaf(rs - 1.0f, wf, 1.0f);
        const float* cr = cumS + hh*128;
        unsigned bits = qq * T1;
        unsigned step = qq << 12;
        float e_cur = (ilo >= 0) ? cr[ilo] : cr[15];
        float env0  = (ilo >= 0) ? 0.0f : cr[0];      // only used when ilo<0, r=0
        #pragma unroll
        for (int r=0;r<8;r++){
            float env;
            if (r == 0 && ilo < 0) env = env0;                       // low clamp: wf=0
            else env = (ilo == 15 && r == 7) ? e_cur : e_cur*mix;    // high clamp at lo=127
            float m = (float)bits * 2.3283064365386963e-10f;
            float sv; asm("v_sin_f32 %0, %1" : "=v"(sv) : "v"(m));
            acc[r] = fmaf(env, sv, acc[r]);
            bits += step;
            if (!(r == 0 && ilo < 0)) e_cur *= rs16;
        }
    }
    const float* la = locraw + (size_t)lc*NSAMP;
    float2 v[16];
    #pragma unroll
    for (int r=0;r<8;r++) v[r] = make_float2(la[j + 4096*r], acc[r]);
    #pragma unroll
    for (int r=8;r<16;r++) v[r] = make_float2(0.f,0.f);
    __syncthreads();                       // cumS/qS/rS reads done before lds reuse
    n1_tail<-1>(v, lds, t, p, dst + (size_t)lc*NPAD);
}

// stages (Ns=256, 4096) of 65536-FFT; NSTORE=8 skips discarded upper half.
template<int DIR, int NSTORE>
__global__ __launch_bounds__(256) void mfk_f23(const float2* __restrict__ src,
                                               float2* __restrict__ dst)
{
    __shared__ float2 lds[4096];
    int t = threadIdx.x, p = blockIdx.x;
    size_t boff = (size_t)blockIdx.y * NPAD;
    int a = t>>4, w = t&15;
    int j = 256*a + 16*p + w;
    const float2* x = src + boff;
    float2 v[16];
    #pragma unroll
    for (int r=0;r<16;r++) v[r] = x[j + 4096*r];
    int jm = 16*p + w;
    if (jm) twiddle<16>(v, (DIR<0?-TWO_PI:TWO_PI)*(float)jm*(1.0f/4096.0f));
    fft16r<DIR>(v);
    #pragma unroll
    for (int r=0;r<16;r++) lds[lxs(256*a + 16*r + w)] = v[slot16(r)];
    __syncthreads();
    #pragma unroll
    for (int q=0;q<16;q++) v[q] = lds[lxs(256*q + t)];
    if (j) twiddle<16>(v, (DIR<0?-TWO_PI:TWO_PI)*(float)j*(1.0f/65536.0f));
    fft16r<DIR>(v);
    float2* yo = dst + boff + j;
    #pragma unroll
    for (int r=0;r<NSTORE;r++) yo[4096*r] = v[slot16(r)];
}

// ---------------- spectral product + event-sum (linearity) ----------------
__global__ __launch_bounds__(256) void mfk_prodacc(const float2* __restrict__ Z,
        float2* __restrict__ T, int g0, int G, int addTo)
{
    int x = blockIdx.x;
    int beta = blockIdx.y;
    int z = blockIdx.z;
    int g = ((x>>4)<<3) | (x&7);
    int kb = (x&8) ? (255 - g) : g;
    int k = kb*256 + threadIdx.x;
    int km = (NPAD - k) & (NPAD-1);
    int cstart = max(64*beta + 32*z, g0);
    int cend   = min(64*beta + 32*z + 32, g0+G);
    float2 S0 = make_float2(0.f,0.f), S1 = make_float2(0.f,0.f);
    #pragma unroll 4
    for (int c=cstart; c<cend; ++c){
        const float2* zp = Z + (size_t)(c-g0)*NPAD;
        float2 a = zp[k], am = zp[km];
        float2 A0 = make_float2(0.5f*(a.x+am.x), 0.5f*(a.y-am.y));
        float2 R0 = make_float2(0.5f*(a.y+am.y), -0.5f*(a.x-am.x));
        float2 P = cxmul(A0,R0);
        if ((c>>5)&1){ S1.x += P.x; S1.y += P.y; }
        else         { S0.x += P.x; S0.y += P.y; }
    }
    const float s = 1.0f/65536.0f;
    float2 q = make_float2((S0.x - S1.y)*s, (S0.y + S1.x)*s);
    size_t idx = ((size_t)z*2 + beta)*NPAD + k;
    if (addTo){ float2 o = T[idx]; q.x += o.x; q.y += o.y; }
    T[idx] = q;
}

// plain first inverse pair (Ns=1,16), summing the two z-half partial spectra
__global__ __launch_bounds__(256) void mfk_plain_f01(const float2* __restrict__ T,
        float2* __restrict__ dst)
{
    __shared__ float2 lds[4096];
    int t = threadIdx.x, p = blockIdx.x, b = blockIdx.y;
    const float2* x0 = T + (size_t)b*NPAD;
    const float2* x1 = T + (size_t)(2+b)*NPAD;
    int j = 256*(t>>4) + 16*p + (t&15);
    float2 v[16];
    #pragma unroll
    for (int r=0;r<16;r++){
        float2 u0 = x0[j + 4096*r], u1 = x1[j + 4096*r];
        v[r] = make_float2(u0.x+u1.x, u0.y+u1.y);
    }
    n1_tail<1>(v, lds, t, p, dst + (size_t)b*NPAD);
}

// wet chain first pair: drypack (reads located from U2) + stages (Ns=1,16)
__global__ __launch_bounds__(256) void mfk_dry_f01(const float2* __restrict__ U2,
        const float* __restrict__ rmA, const float* __restrict__ IR, float2* __restrict__ dst)
{
    __shared__ float2 lds[4096];
    int t = threadIdx.x, p = blockIdx.x, b = blockIdx.y;
    int j = 256*(t>>4) + 16*p + (t&15);
    float rm[8];
    #pragma unroll
    for (int r=0;r<8;r++) rm[r] = rmA[b*8+r];
    const float2* Ub = U2 + (size_t)(b>>1)*NPAD;
    float2 v[16];
    #pragma unroll
    for (int r=0;r<8;r++){
        int n = j + 4096*r;
        float2 lcv = Ub[n];
        float locv = (b&1) ? lcv.y : lcv.x;
        float iv = 0.f;
        #pragma unroll
        for (int q=0;q<8;q++) iv += rm[q]*IR[(size_t)q*NSAMP + n];
        v[r] = make_float2(locv, iv);
    }
    #pragma unroll
    for (int r=8;r<16;r++) v[r] = make_float2(0.f,0.f);
    n1_tail<-1>(v, lds, t, p, dst + (size_t)b*NPAD);
}

// Hermitian-pair product + stages (Ns=1,16) — wet chain (2 batch-pairs).
__global__ __launch_bounds__(256) void mfk_prod_f01(const float2* __restrict__ Z,
        float2* __restrict__ dst)
{
    __shared__ float2 lds[4096];
    int t = threadIdx.x;
    int px = blockIdx.x;
    int p = (px < 8) ? px : 23 - px;
    int pr = blockIdx.y;
    const float2* z0 = Z + (size_t)(2*pr)*NPAD;
    const float2* z1 = z0 + NPAD;
    int j = 256*(t>>4) + 16*p + (t&15);
    float2 v[16];
    #pragma unroll
    for (int r=0;r<16;r++){
        int k = j + 4096*r;
        int km = (NPAD - k) & (NPAD-1);
        float2 a = z0[k], am = z0[km];
        float2 A0 = make_float2(0.5f*(a.x+am.x), 0.5f*(a.y-am.y));
        float2 R0 = make_float2(0.5f*(a.y+am.y), -0.5f*(a.x-am.x));
        float2 P0 = cxmul(A0,R0);
        float2 b = z1[k], bm = z1[km];
        float2 A1 = make_float2(0.5f*(b.x+bm.x), 0.5f*(b.y-bm.y));
        float2 R1 = make_float2(0.5f*(b.y+bm.y), -0.5f*(b.x-bm.x));
        float2 P1 = cxmul(A1,R1);
        const float s = 1.0f/65536.0f;
        v[r] = make_float2((P0.x - P1.y)*s, (P0.y + P1.x)*s);
    }
    n1_tail<1>(v, lds, t, p, dst + (size_t)pr*NPAD);
}

// wet chain last pair: stages (256,4096) + final mix (dry from U2), writes out
__global__ __launch_bounds__(256) void mfk_f23_final(const float2* __restrict__ src,
        const float2* __restrict__ U2, const float* __restrict__ mxA,
        float* __restrict__ out)
{
    __shared__ float2 lds[4096];
    int t = threadIdx.x, p = blockIdx.x;
    int pr = blockIdx.y;
    size_t boff = (size_t)pr * NPAD;
    int a = t>>4, w = t&15;
    int j = 256*a + 16*p + w;
    const float2* x = src + boff;
    float2 v[16];
    #pragma unroll
    for (int r=0;r<16;r++) v[r] = x[j + 4096*r];
    int jm = 16*p + w;
    if (jm) twiddle<16>(v, TWO_PI*(float)jm*(1.0f/4096.0f));
    fft16r<1>(v);
    #pragma unroll
    for (int r=0;r<16;r++) lds[lxs(256*a + 16*r + w)] = v[slot16(r)];
    __syncthreads();
    #pragma unroll
    for (int q=0;q<16;q++) v[q] = lds[lxs(256*q + t)];
    if (j) twiddle<16>(v, TWO_PI*(float)j*(1.0f/65536.0f));
    fft16r<1>(v);
    int b0 = 2*pr, b1 = b0+1;
    float mx0 = mxA[b0], mx1 = mxA[b1];
    const float2* Ub = U2 + (size_t)pr*NPAD;
    #pragma unroll
    for (int r=0;r<8;r++){
        int ts = j + 4096*r;
        float2 val = v[slot16(r)];
        float2 dry = Ub[ts];
        out[(size_t)b0*NSAMP+ts] = dry.x*(1.f-mx0) + val.x*mx0;
        out[(size_t)b1*NSAMP+ts] = dry.y*(1.f-mx1) + val.y*mx1;
    }
}

extern "C" void kernel_launch(void* const* d_in, const int* in_sizes, int n_in,
                              void* d_out, int out_size, void* d_ws, size_t ws_size,
                              hipStream_t stream)
{
    (void)in_sizes; (void)n_in; (void)out_size;
    const float* EP   = (const float*)d_in[0];
    const float* MXR  = (const float*)d_in[1];
    const float* RL   = (const float*)d_in[2];
    const float* NOISE= (const float*)d_in[3];
    const float* IR   = (const float*)d_in[4];
    float* out = (float*)d_out;
    char* w = (char*)d_ws;

    auto need = [](long long g)->long long {
        return 2LL*g*NPAD*8 + 1LL*g*NSAMP*4 + (long long)NSAMP*8
             + 2048LL*128*4 + (128LL*8 + 2048 + 2048 + 4 + 32)*4
             + 4LL*NPAD*8 /*T*/ + 2LL*NPAD*8 /*U2*/ + 16384;
    };
    int G = 128;
    while (G > 4 && need(G) > (long long)ws_size) G >>= 1;

    size_t off = 0;
    auto alloc = [&](size_t bytes)->char* {
        char* p = w + off; off += (bytes + 255) & ~(size_t)255; return p;
    };
    float2*   arA    = (float2*)alloc((size_t)G*NPAD*8);
    float2*   arB    = (float2*)alloc((size_t)G*NPAD*8);
    float*    locraw = (float*) alloc((size_t)G*NSAMP*4);
    float2*   T      = (float2*)alloc(4LL*NPAD*8);   // [z][beta] partial spectra
    float2*   U2     = (float2*)alloc(2LL*NPAD*8);   // packed located per batch-pair
    float2*   nspec  = (float2*)alloc((size_t)NSAMP*8);
    float*    cum    = (float*) alloc(2048LL*128*4); // [q][jj] (R11 layout)
    float*    chP    = (float*) alloc(128*8*4);
    unsigned* chQ    = (unsigned*)alloc(2048*4);
    float*    chR    = (float*) alloc(2048*4);
    float*    mxA    = (float*) alloc(4*4);
    float*    rmA    = (float*) alloc(32*4);

    // noise N1 (blocks 0..7) + full setup (blocks 8..15)
    mfk_n1_noise_setup<<<dim3(16),256,0,stream>>>(NOISE, arB, EP, MXR, RL,
                                                  chP, chQ, chR, cum, mxA, rmA);
    mfk_n2_noise<<<dim3(8),256,0,stream>>>(arB, nspec);

    for (int g0 = 0; g0 < NCH; g0 += G){
        int P = G/2;
        mfk_n1_specwin<<<dim3(8,P),256,0,stream>>>(nspec, chP, arA, g0);
        mfk_n2_unpack<<<dim3(8,P),256,0,stream>>>(arA, chP, locraw, g0);
        mfk_packZres_f01<<<dim3(16,G),256,0,stream>>>(locraw, chQ, chR, cum, arA, g0);
        mfk_f23<-1,16><<<dim3(16,G),256,0,stream>>>(arA, arB);
        mfk_prodacc<<<dim3(256,2,2),256,0,stream>>>(arB, T, g0, G, (g0>0)?1:0);
    }

    // single packed inverse (2 batch-pairs)
    mfk_plain_f01<<<dim3(16,2),256,0,stream>>>(T, arB);
    mfk_f23<1,8><<<dim3(16,2),256,0,stream>>>(arB, U2);

    // wet/dry chain (batch 4 -> 2 pairs), dry taken from U2
    mfk_dry_f01<<<dim3(16,4),256,0,stream>>>(U2, rmA, IR, arA);
    mfk_f23<-1,16><<<dim3(16,4),256,0,stream>>>(arA, arB);
    mfk_prod_f01<<<dim3(16,2),256,0,stream>>>(arB, arA);
    mfk_f23_final<<<dim3(16,2),256,0,stream>>>(arA, U2, mxA, out);
}